// Round 12
// baseline (32677.362 us; speedup 1.0000x reference)
//
#include <hip/hip_runtime.h>
#include <math.h>

// HMM forward: alpha_t = (alpha_{t-1} @ A) * B[:, se[t]],  out = -log(sum(alpha_{T-1}))
// N_STATES=2048, N_OBS=8192, T=8192.
//
// R12: per-WAVE column ownership, zero reduction stage.
// 64 blk x 8 waves = 512 waves; wave gw owns cols [4gw,4gw+4), FULL j-range.
// Lane holds A[4*lane+256k+m][4 cols] (k=0..7, m=0..3) = 128 f32 regs.
// Per step: 8x ds_read_b128 (conflict-free) + 128 FMA -> 6-hop butterfly
// -> lanes 0..3 publish 4 tagged u64 packets {tag|f32} immediately (NO
// barrier, NO wave-0 reduce) -> cooperative gather: wave w polls+gathers
// slice [256w,256w+256) into alpha_sm[t&1] (R5's proven ==tag poll) ->
// ONE barrier. alpha_sm parity-double-buffered so gather never races dot.

#define NS    2048
#define NOBS  8192
#define TSEQ  8192
#define NBLK  64
#define NTHR  512

typedef unsigned long long u64;
typedef unsigned int u32;

#define K_LIST(X) X(0) X(1) X(2) X(3) X(4) X(5) X(6) X(7)

__global__ void __launch_bounds__(256) init_ws_kernel(u64* aP) {
  const int i = threadIdx.x;              // 1 block x 256 thr; 4096 u64 total
#pragma unroll
  for (int c = 0; c < 16; ++c) {
    __hip_atomic_store(&aP[i * 16 + c], 0ull, __ATOMIC_RELAXED, __HIP_MEMORY_SCOPE_AGENT);
  }
}

__global__ void __launch_bounds__(NTHR, 2) hmm_forward_kernel(
    const float* __restrict__ Pi0,
    const float* __restrict__ A,
    const float* __restrict__ B,
    const int*   __restrict__ se,
    float* __restrict__ out,
    u64*   __restrict__ aP) {          // [2][NS] tagged alpha packets
  __shared__ __align__(16) float alpha_sm[2][NS];   // parity double buffer

  const int tid  = threadIdx.x;
  const int blk  = blockIdx.x;
  const int w    = tid >> 6;           // wave 0..7
  const int lane = tid & 63;
  const int gw   = blk * 8 + w;        // global wave 0..511
  const int c0   = gw * 4;             // owned output-column base
  const int jrow = 4 * lane;           // lane's j within each 256-chunk

  // ---- A fragments: Ar{k}_{m} = A[jrow + 256k + m][c0..c0+3]
#define DECA(k) float4 Ar##k##_0, Ar##k##_1, Ar##k##_2, Ar##k##_3;
  K_LIST(DECA)
#define LOADA(k) { const float* ap = A + (size_t)(jrow + 256 * k) * NS + c0; \
    Ar##k##_0 = *reinterpret_cast<const float4*>(ap); \
    Ar##k##_1 = *reinterpret_cast<const float4*>(ap + NS); \
    Ar##k##_2 = *reinterpret_cast<const float4*>(ap + 2 * NS); \
    Ar##k##_3 = *reinterpret_cast<const float4*>(ap + 3 * NS); }
  K_LIST(LOADA)
#define PIN1(f) asm volatile("" : "+v"(f.x), "+v"(f.y), "+v"(f.z), "+v"(f.w));
#define PINA(k) PIN1(Ar##k##_0) PIN1(Ar##k##_1) PIN1(Ar##k##_2) PIN1(Ar##k##_3)
  K_LIST(PINA)

  // ---- alpha_0 = Pi0 * B[:, se[0]] into parity-0 buffer
  {
    const int s0 = se[0];
#pragma unroll
    for (int c = 0; c < 4; ++c) {
      const int i = tid * 4 + c;
      alpha_sm[0][i] = Pi0[i] * B[(size_t)i * NOBS + s0];
    }
  }
  __syncthreads();

  // ---- emission prefetch pipeline (lanes 0..3 of every wave publish)
  float bv_next = 0.f;
  if (lane < 4) bv_next = B[(size_t)(c0 + lane) * NOBS + se[1]];
  int sidx_n2 = se[2 < TSEQ ? 2 : TSEQ - 1];

  for (int t = 1; t < TSEQ; ++t) {
    const float bv  = bv_next;
    const int   buf = t & 1;
    const float* smb = alpha_sm[buf ^ 1];    // alpha_{t-1}
    if (lane < 4) bv_next = B[(size_t)(c0 + lane) * NOBS + sidx_n2];
    {
      const int tn2 = (t + 2 < TSEQ) ? (t + 2) : (TSEQ - 1);
      sidx_n2 = se[tn2];
    }

    // ---- dot: full j-range for 4 columns; 8 conflict-free b128 reads,
    //      128 FMA in 16 independent chains
    float4 acc0 = {0.f,0.f,0.f,0.f}, acc1 = {0.f,0.f,0.f,0.f};
    float4 acc2 = {0.f,0.f,0.f,0.f}, acc3 = {0.f,0.f,0.f,0.f};
#define DOT(k) { const float4 av = *reinterpret_cast<const float4*>(&smb[jrow + 256 * k]); \
    acc0.x = fmaf(av.x, Ar##k##_0.x, acc0.x); acc0.y = fmaf(av.x, Ar##k##_0.y, acc0.y); \
    acc0.z = fmaf(av.x, Ar##k##_0.z, acc0.z); acc0.w = fmaf(av.x, Ar##k##_0.w, acc0.w); \
    acc1.x = fmaf(av.y, Ar##k##_1.x, acc1.x); acc1.y = fmaf(av.y, Ar##k##_1.y, acc1.y); \
    acc1.z = fmaf(av.y, Ar##k##_1.z, acc1.z); acc1.w = fmaf(av.y, Ar##k##_1.w, acc1.w); \
    acc2.x = fmaf(av.z, Ar##k##_2.x, acc2.x); acc2.y = fmaf(av.z, Ar##k##_2.y, acc2.y); \
    acc2.z = fmaf(av.z, Ar##k##_2.z, acc2.z); acc2.w = fmaf(av.z, Ar##k##_2.w, acc2.w); \
    acc3.x = fmaf(av.w, Ar##k##_3.x, acc3.x); acc3.y = fmaf(av.w, Ar##k##_3.y, acc3.y); \
    acc3.z = fmaf(av.w, Ar##k##_3.z, acc3.z); acc3.w = fmaf(av.w, Ar##k##_3.w, acc3.w); }
    K_LIST(DOT)
    float4 sv;
    sv.x = (acc0.x + acc1.x) + (acc2.x + acc3.x);
    sv.y = (acc0.y + acc1.y) + (acc2.y + acc3.y);
    sv.z = (acc0.z + acc1.z) + (acc2.z + acc3.z);
    sv.w = (acc0.w + acc1.w) + (acc2.w + acc3.w);

    // ---- 6-hop butterfly: all lanes end with the 4 full column sums
#pragma unroll
    for (int off = 32; off; off >>= 1) {
      sv.x += __shfl_xor(sv.x, off);
      sv.y += __shfl_xor(sv.y, off);
      sv.z += __shfl_xor(sv.z, off);
      sv.w += __shfl_xor(sv.w, off);
    }

    // ---- publish immediately (no barrier, no reduce stage)
    u64* base = aP + (size_t)buf * NS;
    if (lane < 4) {
      const float vsel = (lane == 0) ? sv.x : (lane == 1) ? sv.y
                        : (lane == 2) ? sv.z : sv.w;
      const u64 pkt = (u64)__float_as_uint(vsel * bv) | ((u64)(u32)t << 32);
      __hip_atomic_store(&base[c0 + lane], pkt, __ATOMIC_RELAXED, __HIP_MEMORY_SCOPE_AGENT);
    }
    asm volatile("" ::: "memory");   // keep the publish above the poll loop

    // ---- cooperative gather (R5's proven poll): wave w owns slice 256w
    {
      const u64* src = base + w * 256 + lane * 4;
      u64 q0, q1, q2, q3;
      const u32 tag = (u32)t;
      for (;;) {
        q0 = __hip_atomic_load(&src[0], __ATOMIC_RELAXED, __HIP_MEMORY_SCOPE_AGENT);
        q1 = __hip_atomic_load(&src[1], __ATOMIC_RELAXED, __HIP_MEMORY_SCOPE_AGENT);
        q2 = __hip_atomic_load(&src[2], __ATOMIC_RELAXED, __HIP_MEMORY_SCOPE_AGENT);
        q3 = __hip_atomic_load(&src[3], __ATOMIC_RELAXED, __HIP_MEMORY_SCOPE_AGENT);
        if ((u32)(q0 >> 32) == tag && (u32)(q1 >> 32) == tag &&
            (u32)(q2 >> 32) == tag && (u32)(q3 >> 32) == tag) break;
      }
      float4 v;
      v.x = __uint_as_float((u32)q0);
      v.y = __uint_as_float((u32)q1);
      v.z = __uint_as_float((u32)q2);
      v.w = __uint_as_float((u32)q3);
      *reinterpret_cast<float4*>(&alpha_sm[buf][w * 256 + lane * 4]) = v;
    }
    __syncthreads();   // the ONE barrier: all slices of alpha_t visible
  }

  // ---- final: -log(sum(alpha_{T-1})), block 0 (last parity = 1)
  if (blk == 0) {
    const float* smf = alpha_sm[(TSEQ - 1) & 1];
    float s = 0.f;
#pragma unroll
    for (int c = 0; c < 4; ++c) s += smf[tid * 4 + c];
#pragma unroll
    for (int off = 32; off; off >>= 1) s += __shfl_xor(s, off);
    __syncthreads();
    if (lane == 0) alpha_sm[0][w] = s;   // reuse parity-0 buffer as scratch
    __syncthreads();
    if (tid == 0) {
      float S = 0.f;
#pragma unroll
      for (int ww = 0; ww < 8; ++ww) S += alpha_sm[0][ww];
      out[0] = -logf(S);
    }
  }
}

extern "C" void kernel_launch(void* const* d_in, const int* in_sizes, int n_in,
                              void* d_out, int out_size, void* d_ws, size_t ws_size,
                              hipStream_t stream) {
  const float* Pi0 = (const float*)d_in[0];
  const float* A   = (const float*)d_in[1];
  const float* B   = (const float*)d_in[2];
  const int*   se  = (const int*)d_in[3];
  float*       out = (float*)d_out;

  // ws layout: aP = u64[2][NS] tagged alpha packets (32 KiB) at offset 0
  u64* aP = (u64*)d_ws;

  init_ws_kernel<<<1, 256, 0, stream>>>(aP);   // zero all tags (every launch)
  hmm_forward_kernel<<<NBLK, NTHR, 0, stream>>>(Pi0, A, B, se, out, aP);
}

// Round 13
// 17419.756 us; speedup vs baseline: 1.8759x; 1.8759x over previous
//
#include <hip/hip_runtime.h>
#include <math.h>

// HMM forward: alpha_t = (alpha_{t-1} @ A) * B[:, se[t]],  out = -log(sum(alpha_{T-1}))
// N_STATES=2048, N_OBS=8192, T=8192.
//
// FINAL (best-known = R10, 17.42 ms):
// 64 blk x 512 thr. A in 128 f32 regs/thread (pinned; unified VGPR/AGPR file).
// Tagged-dataflow exchange: alpha published as u64 {tag:32|f32:32} agent-scope
// relaxed atomics (data==readiness, single LLC round trip); each wave polls and
// gathers only its own 256-float j-slice. ONE __syncthreads per step.
// Per-step critical path = compute (overlapped) + ~2 LLC RTs (publish-commit,
// detect+deliver) + max-over-64-blocks jitter ~= 2.13 us — the structural
// floor for a device-wide sequential all-to-all recurrence on this chip.
// Falsified alternatives: poll backoff (R6), flag+data split (R7), per-wave
// all-gather (R8), 256-block spread (R9, 32-way LDS conflicts), pipelined
// poll (R11), per-wave no-reduce (R12).

#define NS    2048
#define NOBS  8192
#define TSEQ  8192
#define NBLK  64
#define NTHR  512
#define OPB   32              // output columns per block
#define JPT   128             // j-slice length per thread

typedef unsigned long long u64;
typedef unsigned int u32;

// X-macro over the 32 float4 A-fragments
#define A_LIST(X) \
  X(0)  X(1)  X(2)  X(3)  X(4)  X(5)  X(6)  X(7)  \
  X(8)  X(9)  X(10) X(11) X(12) X(13) X(14) X(15) \
  X(16) X(17) X(18) X(19) X(20) X(21) X(22) X(23) \
  X(24) X(25) X(26) X(27) X(28) X(29) X(30) X(31)

__global__ void __launch_bounds__(256) init_ws_kernel(u64* aP) {
  const int i = threadIdx.x;              // 1 block x 256 thr; 4096 u64 total
#pragma unroll
  for (int c = 0; c < 16; ++c) {
    __hip_atomic_store(&aP[i * 16 + c], 0ull, __ATOMIC_RELAXED, __HIP_MEMORY_SCOPE_AGENT);
  }
}

__global__ void __launch_bounds__(NTHR, 2) hmm_forward_kernel(
    const float* __restrict__ Pi0,
    const float* __restrict__ A,
    const float* __restrict__ B,
    const int*   __restrict__ se,
    float* __restrict__ out,
    u64*   __restrict__ aP) {          // [2][NS] tagged alpha
  __shared__ __align__(16) float alpha_sm[NS];
  __shared__ float red[2][NTHR / 64][OPB];   // [parity][wave][o] (conflict-free)

  const int tid    = threadIdx.x;
  const int blk    = blockIdx.x;
  const int w      = tid >> 6;       // wave 0..7
  const int lane   = tid & 63;
  const int h      = lane >> 5;      // half-wave
  const int o      = lane & 31;      // output slot within block
  const int i_mine = blk * OPB + o;  // owned output column
  const int jbase  = (w * 2 + h) * JPT;

  // ---- A column-slice into 32 named float4 SSA registers:
  //      Ar{k} = A[jbase+4k .. jbase+4k+3][i_mine]
#define DECLA(k) float4 Ar##k;
  A_LIST(DECLA)
#define LOADA(k) { const float* ap = A + (size_t)(jbase + 4 * k) * NS + i_mine; \
                   Ar##k.x = ap[0]; Ar##k.y = ap[NS]; Ar##k.z = ap[2 * NS]; Ar##k.w = ap[3 * NS]; }
  A_LIST(LOADA)
  // Opaque pin: asm-defined scalars cannot be refolded/remat'd into the loop.
#define PIN4(k) asm volatile("" : "+v"(Ar##k.x), "+v"(Ar##k.y), "+v"(Ar##k.z), "+v"(Ar##k.w));
  A_LIST(PIN4)

  // ---- alpha_0 = Pi0 * B[:, se[0]], computed redundantly by every block
  {
    const int s0 = se[0];
#pragma unroll
    for (int c = 0; c < 4; ++c) {
      const int i = tid * 4 + c;
      alpha_sm[i] = Pi0[i] * B[(size_t)i * NOBS + s0];
    }
  }
  __syncthreads();

  // ---- emission prefetch pipeline (publishing lanes tid<32 only):
  // bv_next = B value for step 1; sidx_n2 = se row for step 2.
  float bv_next = 0.f;
  if (tid < OPB) bv_next = B[(size_t)i_mine * NOBS + se[1]];
  int sidx_n2 = se[2 < TSEQ ? 2 : TSEQ - 1];

  for (int t = 1; t < TSEQ; ++t) {
    const float bv  = bv_next;
    const int   buf = t & 1;
    // B row for step t+1 already known (sidx_n2) -> load issues immediately
    if (tid < OPB) bv_next = B[(size_t)i_mine * NOBS + sidx_n2];
    {  // se row for step t+2 (consumed next iteration; fully hidden)
      const int tn2 = (t + 2 < TSEQ) ? (t + 2) : (TSEQ - 1);
      sidx_n2 = se[tn2];
    }

    // ---- dot over this thread's 128-long j-slice (alpha from LDS, A in regs)
    float a0 = 0.f, a1 = 0.f, a2 = 0.f, a3 = 0.f;
#define DOT(k) { const float4 av = *reinterpret_cast<const float4*>(&alpha_sm[jbase + 4 * k]); \
                 a0 = fmaf(Ar##k.x, av.x, a0); a1 = fmaf(Ar##k.y, av.y, a1); \
                 a2 = fmaf(Ar##k.z, av.z, a2); a3 = fmaf(Ar##k.w, av.w, a3); }
    A_LIST(DOT)
    float acc = (a0 + a1) + (a2 + a3);
    acc += __shfl_xor(acc, 32);        // combine the two half-wave j-slices
    if (lane < 32) red[buf][w][o] = acc;
    __syncthreads();   // the ONE barrier per step: red[buf] handoff to wave 0

    // ---- wave 0: finish reduction, apply emission, publish tagged alpha_t
    if (w == 0) {
      __builtin_amdgcn_s_setprio(1);   // critical section vs polling waves
      float s = 0.f;
#pragma unroll
      for (int ww = 0; ww < NTHR / 64; ++ww) s += red[buf][ww][o];
      if (lane < 32) {
        const float aval = s * bv;
        const u64 pkt = (u64)__float_as_uint(aval) | ((u64)(u32)t << 32);
        __hip_atomic_store(&aP[(size_t)buf * NS + blk * OPB + o], pkt,
                           __ATOMIC_RELAXED, __HIP_MEMORY_SCOPE_AGENT);
      }
      __builtin_amdgcn_s_setprio(0);
    }

    // ---- each wave gathers ITS OWN 256-float j-slice by tag-poll
    // (data==readiness: one LLC round trip detects and delivers)
    {
      const u64* src = aP + (size_t)buf * NS + w * 256 + lane * 4;
      u64 q0, q1, q2, q3;
      const u32 tag = (u32)t;
      for (;;) {
        q0 = __hip_atomic_load(&src[0], __ATOMIC_RELAXED, __HIP_MEMORY_SCOPE_AGENT);
        q1 = __hip_atomic_load(&src[1], __ATOMIC_RELAXED, __HIP_MEMORY_SCOPE_AGENT);
        q2 = __hip_atomic_load(&src[2], __ATOMIC_RELAXED, __HIP_MEMORY_SCOPE_AGENT);
        q3 = __hip_atomic_load(&src[3], __ATOMIC_RELAXED, __HIP_MEMORY_SCOPE_AGENT);
        if ((u32)(q0 >> 32) == tag && (u32)(q1 >> 32) == tag &&
            (u32)(q2 >> 32) == tag && (u32)(q3 >> 32) == tag) break;
      }
      float4 v;
      v.x = __uint_as_float((u32)q0);
      v.y = __uint_as_float((u32)q1);
      v.z = __uint_as_float((u32)q2);
      v.w = __uint_as_float((u32)q3);
      *reinterpret_cast<float4*>(&alpha_sm[w * 256 + lane * 4]) = v;
    }
    // no barrier: next dot reads only this wave's own slice
  }

  // ---- final: -log(sum(alpha_{T-1})), block 0 only
  if (blk == 0) {
    __syncthreads();   // all waves' final gathers into alpha_sm
    float s = 0.f;
#pragma unroll
    for (int c = 0; c < 4; ++c) s += alpha_sm[4 * tid + c];
#pragma unroll
    for (int off = 32; off > 0; off >>= 1) s += __shfl_xor(s, off);
    if (lane == 0) red[0][w][0] = s;
    __syncthreads();
    if (tid == 0) {
      float S = 0.f;
#pragma unroll
      for (int ww = 0; ww < NTHR / 64; ++ww) S += red[0][ww][0];
      out[0] = -logf(S);
    }
  }
}

extern "C" void kernel_launch(void* const* d_in, const int* in_sizes, int n_in,
                              void* d_out, int out_size, void* d_ws, size_t ws_size,
                              hipStream_t stream) {
  const float* Pi0 = (const float*)d_in[0];
  const float* A   = (const float*)d_in[1];
  const float* B   = (const float*)d_in[2];
  const int*   se  = (const int*)d_in[3];
  float*       out = (float*)d_out;

  // ws layout: aP = u64[2][NS] tagged alpha packets (32 KiB) at offset 0
  u64* aP = (u64*)d_ws;

  init_ws_kernel<<<1, 256, 0, stream>>>(aP);   // zero all tags (every launch)
  hmm_forward_kernel<<<NBLK, NTHR, 0, stream>>>(Pi0, A, B, se, out, aP);
}